// Round 5
// baseline (225.538 us; speedup 1.0000x reference)
//
#include <hip/hip_runtime.h>

typedef unsigned short u16;
typedef unsigned int u32;

#define DM 1024
#define NH 16
#define DH 64
#define BB 2
#define TT 2048

// Q pre-scale: (1/sqrt(64)) * log2(e)
#define SCLQ 0.18033688f

using frag8  = __attribute__((ext_vector_type(8))) short;
using bf16x8 = __attribute__((ext_vector_type(8))) __bf16;
using f32x4  = __attribute__((ext_vector_type(4))) float;

__device__ inline u16 f2bf(float f) {
  union { float f; u32 u; } v; v.f = f;
  u32 r = v.u + 0x7fffu + ((v.u >> 16) & 1u);
  return (u16)(r >> 16);
}

__device__ inline f32x4 mfma_bf16(frag8 a, frag8 b, f32x4 c) {
  return __builtin_amdgcn_mfma_f32_16x16x32_bf16(
      __builtin_bit_cast(bf16x8, a), __builtin_bit_cast(bf16x8, b), c, 0, 0, 0);
}

// async global->LDS, 16B/lane; LDS dest = base + lane*16 (wave-uniform base)
__device__ inline void gld16(void* lds, const void* g) {
  __builtin_amdgcn_global_load_lds(
      (const __attribute__((address_space(1))) void*)g,
      (__attribute__((address_space(3))) void*)lds, 16, 0, 0);
}

// swizzled LDS index (u16 units) for 64-u16 rows: 8 chunks of 16B,
// stored chunk position = chunk ^ (row & 7)
__device__ inline int swi(int row, int chunk) {
  return row * 64 + ((chunk ^ (row & 7)) << 3);
}

// ---------- x -> bf16 ----------
__global__ __launch_bounds__(256) void cvt_x_kernel(const float* __restrict__ X,
                                                    u16* __restrict__ Y) {
  int i = blockIdx.x * 256 + threadIdx.x;
  float4 v = ((const float4*)X)[i];
  ushort4 o;
  o.x = f2bf(v.x); o.y = f2bf(v.y); o.z = f2bf(v.z); o.w = f2bf(v.w);
  ((ushort4*)Y)[i] = o;
}

// ---------- W (K,N) fp32 -> Wt (N,K) bf16, tiled ----------
__global__ __launch_bounds__(256) void transpose_w_kernel(
    const float* __restrict__ W0, const float* __restrict__ W1,
    const float* __restrict__ W2, const float* __restrict__ W3,
    u16* __restrict__ O0, u16* __restrict__ O1,
    u16* __restrict__ O2, u16* __restrict__ O3) {
  const float* W; u16* Ot;
  switch (blockIdx.z) {
    case 0: W = W0; Ot = O0; break;
    case 1: W = W1; Ot = O1; break;
    case 2: W = W2; Ot = O2; break;
    default: W = W3; Ot = O3; break;
  }
  __shared__ u16 Ls[64][72];
  int tid = threadIdx.x;
  int n0 = blockIdx.x * 64;
  int k0 = blockIdx.y * 64;
#pragma unroll
  for (int p = 0; p < 4; ++p) {
    int id = tid + p * 256;
    int row = id >> 4;
    int c4 = (id & 15) * 4;
    float4 v = *(const float4*)&W[(size_t)(k0 + row) * DM + n0 + c4];
    ushort4 o; o.x = f2bf(v.x); o.y = f2bf(v.y); o.z = f2bf(v.z); o.w = f2bf(v.w);
    *(ushort4*)&Ls[row][c4] = o;
  }
  __syncthreads();
#pragma unroll
  for (int p = 0; p < 4; ++p) {
    int id = tid + p * 256;
    int row = id >> 4;
    int c4 = (id & 15) * 4;
    ushort4 o;
    o.x = Ls[c4 + 0][row]; o.y = Ls[c4 + 1][row];
    o.z = Ls[c4 + 2][row]; o.w = Ls[c4 + 3][row];
    *(ushort4*)&Ot[(size_t)(n0 + row) * DM + k0 + c4] = o;
  }
}

// ---------- QKV GEMM (double-buffered, 1 barrier/iter, swizzled LDS) ----------
// col<1024 -> Q*SCLQ into QK; col<2048 -> K into QK; col>=2048 -> V into Vb.
__global__ __launch_bounds__(256, 3) void gemm_qkv_kernel(
    const u16* __restrict__ A, const u16* __restrict__ Bt,
    const float* __restrict__ b0, const float* __restrict__ b1,
    const float* __restrict__ b2,
    u16* __restrict__ QK, u16* __restrict__ Vb) {
  constexpr int K = 1024;
  __shared__ u16 As[2][4096];  // [buf][128 rows x 32 k], chunk-swizzled
  __shared__ u16 Bs[2][4096];
  int tid = threadIdx.x;
  int lane = tid & 63, w = tid >> 6;
  int qd = lane >> 4, ln = lane & 15;
  int wm = (w & 1) * 64, wn = (w >> 1) * 64;
  int m0 = blockIdx.y * 128, n0 = blockIdx.x * 128;
  f32x4 z = {0.f, 0.f, 0.f, 0.f};
  f32x4 acc[4][4];
#pragma unroll
  for (int mi = 0; mi < 4; ++mi)
#pragma unroll
    for (int ni = 0; ni < 4; ++ni) acc[mi][ni] = z;

  // DMA source: content chunk = (lane&3) ^ (row&3), row = w*32 + (lane>>2)
  int csw = ((lane & 3) ^ ((lane >> 2) & 3)) * 8;
  const u16* ga = A + (size_t)(m0 + w * 32 + (lane >> 2)) * K + csw;
  const u16* gb = Bt + (size_t)(n0 + w * 32 + (lane >> 2)) * K + csw;

  gld16(&As[0][w * 1024],       ga);
  gld16(&As[0][w * 1024 + 512], ga + 16 * K);
  gld16(&Bs[0][w * 1024],       gb);
  gld16(&Bs[0][w * 1024 + 512], gb + 16 * K);

  int fsw = (qd ^ (ln & 3)) * 8;  // frag read chunk position
  for (int k0 = 0; k0 < K; k0 += 32) {
    int cur = (k0 >> 5) & 1;
    __syncthreads();
    if (k0 + 32 < K) {
      int nb = cur ^ 1;
      gld16(&As[nb][w * 1024],       ga + k0 + 32);
      gld16(&As[nb][w * 1024 + 512], ga + k0 + 32 + 16 * K);
      gld16(&Bs[nb][w * 1024],       gb + k0 + 32);
      gld16(&Bs[nb][w * 1024 + 512], gb + k0 + 32 + 16 * K);
    }
    frag8 af[4], bfr[4];
#pragma unroll
    for (int mi = 0; mi < 4; ++mi)
      af[mi] = *(const frag8*)&As[cur][(wm + mi * 16 + ln) * 32 + fsw];
#pragma unroll
    for (int ni = 0; ni < 4; ++ni)
      bfr[ni] = *(const frag8*)&Bs[cur][(wn + ni * 16 + ln) * 32 + fsw];
#pragma unroll
    for (int mi = 0; mi < 4; ++mi)
#pragma unroll
      for (int ni = 0; ni < 4; ++ni)
        acc[mi][ni] = mfma_bf16(af[mi], bfr[ni], acc[mi][ni]);
  }

#pragma unroll
  for (int ni = 0; ni < 4; ++ni) {
    int col = n0 + wn + ni * 16 + ln;
    if (col < 2048) {
      bool isq = col < 1024;
      float bias = isq ? b0[col] : b1[col - 1024];
#pragma unroll
      for (int mi = 0; mi < 4; ++mi) {
        int row = m0 + wm + mi * 16 + qd * 4;
#pragma unroll
        for (int r = 0; r < 4; ++r) {
          float v = acc[mi][ni][r] + bias;
          if (isq) v *= SCLQ;
          QK[(size_t)(row + r) * 2048 + col] = f2bf(v);
        }
      }
    } else {
      int c2 = col - 2048;
      float bias = b2[c2];
#pragma unroll
      for (int mi = 0; mi < 4; ++mi) {
        int row = m0 + wm + mi * 16 + qd * 4;
#pragma unroll
        for (int r = 0; r < 4; ++r)
          Vb[(size_t)(row + r) * 1024 + c2] = f2bf(acc[mi][ni][r] + bias);
      }
    }
  }
}

// ---------- out-proj GEMM (double-buffered, swizzled): 128x64, f32 out ----------
__global__ __launch_bounds__(256) void gemm_out_kernel(
    const u16* __restrict__ A, const u16* __restrict__ Bt,
    const float* __restrict__ b0, float* __restrict__ Cf) {
  constexpr int K = 1024;
  __shared__ u16 As[2][4096];  // 128 x 32
  __shared__ u16 Bs[2][2048];  // 64 x 32
  int tid = threadIdx.x;
  int lane = tid & 63, w = tid >> 6;
  int qd = lane >> 4, ln = lane & 15;
  int m0 = blockIdx.y * 128, n0 = blockIdx.x * 64;
  f32x4 z = {0.f, 0.f, 0.f, 0.f};
  f32x4 acc[2][4];
#pragma unroll
  for (int mi = 0; mi < 2; ++mi)
#pragma unroll
    for (int ni = 0; ni < 4; ++ni) acc[mi][ni] = z;

  int csw = ((lane & 3) ^ ((lane >> 2) & 3)) * 8;
  const u16* ga = A + (size_t)(m0 + w * 32 + (lane >> 2)) * K + csw;
  const u16* gb = Bt + (size_t)(n0 + w * 16 + (lane >> 2)) * K + csw;

  gld16(&As[0][w * 1024],       ga);
  gld16(&As[0][w * 1024 + 512], ga + 16 * K);
  gld16(&Bs[0][w * 512],        gb);

  int fsw = (qd ^ (ln & 3)) * 8;
  for (int k0 = 0; k0 < K; k0 += 32) {
    int cur = (k0 >> 5) & 1;
    __syncthreads();
    if (k0 + 32 < K) {
      int nb = cur ^ 1;
      gld16(&As[nb][w * 1024],       ga + k0 + 32);
      gld16(&As[nb][w * 1024 + 512], ga + k0 + 32 + 16 * K);
      gld16(&Bs[nb][w * 512],        gb + k0 + 32);
    }
    frag8 af[2], bfr[4];
#pragma unroll
    for (int mi = 0; mi < 2; ++mi)
      af[mi] = *(const frag8*)&As[cur][(w * 32 + mi * 16 + ln) * 32 + fsw];
#pragma unroll
    for (int ni = 0; ni < 4; ++ni)
      bfr[ni] = *(const frag8*)&Bs[cur][(ni * 16 + ln) * 32 + fsw];
#pragma unroll
    for (int mi = 0; mi < 2; ++mi)
#pragma unroll
      for (int ni = 0; ni < 4; ++ni)
        acc[mi][ni] = mfma_bf16(af[mi], bfr[ni], acc[mi][ni]);
  }

#pragma unroll
  for (int ni = 0; ni < 4; ++ni) {
    int col = n0 + ni * 16 + ln;
    float bias = b0[col];
#pragma unroll
    for (int mi = 0; mi < 2; ++mi) {
      int row = m0 + w * 32 + mi * 16 + qd * 4;
#pragma unroll
      for (int r = 0; r < 4; ++r)
        Cf[(size_t)(row + r) * 1024 + col] = acc[mi][ni][r] + bias;
    }
  }
}

// ---------- V (B,T,D) bf16 -> Vt (B,H,DH,T) bf16, tiled ----------
__global__ __launch_bounds__(256) void transpose_v_kernel(const u16* __restrict__ V,
                                                          u16* __restrict__ Vt) {
  int bh = blockIdx.y;
  int b = bh >> 4, h = bh & 15;
  int t0 = blockIdx.x * 64;
  __shared__ u16 Ls[64][72];
  int tid = threadIdx.x;
#pragma unroll
  for (int p = 0; p < 2; ++p) {
    int id = tid + p * 256;
    int row = id >> 3, seg = id & 7;
    *(uint4*)&Ls[row][seg * 8] =
        *(const uint4*)&V[(size_t)(b * TT + t0 + row) * DM + h * DH + seg * 8];
  }
  __syncthreads();
#pragma unroll
  for (int p = 0; p < 2; ++p) {
    int id = tid + p * 256;
    int d = id >> 3, seg = id & 7;
    union { u16 s[8]; uint4 v; } tmp;
#pragma unroll
    for (int j = 0; j < 8; ++j) tmp.s[j] = Ls[seg * 8 + j][d];
    *(uint4*)&Vt[(size_t)(bh * DH + d) * TT + t0 + seg * 8] = tmp.v;
  }
}

// ---------- flash v5: P via ds_bpermute (no P LDS), 32KB LDS, unpaired ----------
// QK: [B*T][2048] bf16 (Q pre-scaled, K). Vt: [B*H][DH][TT]. O: [B*T][1024] bf16.
__global__ __launch_bounds__(256, 4) void flash5_kernel(const u16* __restrict__ QK,
                                                        const u16* __restrict__ Vt,
                                                        u16* __restrict__ O) {
  int qt = 31 - (int)blockIdx.x;  // longest first
  int bh = blockIdx.y;
  int b = bh >> 4, h = bh & 15;
  int q0 = qt * 64;
  __shared__ u16 Ks[2 * 4096];
  __shared__ u16 Vs[2 * 4096];
  int tid = threadIdx.x;
  int lane = tid & 63, w = tid >> 6;
  int qd = lane >> 4, ln = lane & 15;

  // Q fragments (B-operand: n=ln -> q, k=qd*8+j -> d); Q pre-scaled by SCLQ
  frag8 qf[2];
#pragma unroll
  for (int kk = 0; kk < 2; ++kk)
    qf[kk] = *(const frag8*)&QK[(size_t)(b * TT + q0 + w * 16 + ln) * 2048 +
                                h * 64 + kk * 32 + qd * 8];

  // swizzled global_load_lds staging
  int lr = lane >> 3, lc = (lane & 7) ^ lr;
  const u16* KgA = &QK[(size_t)(b * TT + w * 16 + lr) * 2048 + 1024 + h * 64 + lc * 8];
  const u16* KgB = KgA + 8 * 2048;
  const u16* VgA = &Vt[(size_t)(bh * 64 + w * 16 + lr) * 2048 + lc * 8];
  const u16* VgB = VgA + 8 * 2048;
  int ldsw = w * 1024;

  // bpermute lane indices (x4 bytes): source lane = ((2qd+g)&3)*16 + ln
  int idxg0 = ((((2 * qd) & 3) * 16 + ln) * 4);
  int idxg1 = ((((2 * qd + 1) & 3) * 16 + ln) * 4);

  int nkt = qt + 1;
  gld16(&Ks[ldsw],       KgA);
  gld16(&Ks[ldsw + 512], KgB);
  gld16(&Vs[ldsw],       VgA);
  gld16(&Vs[ldsw + 512], VgB);

  float l_part = 0.f;
  f32x4 z = {0.f, 0.f, 0.f, 0.f};
  f32x4 o_acc[4] = {z, z, z, z};

  for (int kt = 0; kt < nkt; ++kt) {
    int cur = kt & 1;
    int cb = cur * 4096;
    __syncthreads();  // buf[cur] staged; buf[cur^1] readers done

    if (kt + 1 < nkt) {
      int nb = (cur ^ 1) * 4096;
      size_t ko = (size_t)(kt + 1) * 64 * 2048;
      int vo = (kt + 1) * 64;
      gld16(&Ks[nb + ldsw],       KgA + ko);
      gld16(&Ks[nb + ldsw + 512], KgB + ko);
      gld16(&Vs[nb + ldsw],       VgA + vo);
      gld16(&Vs[nb + ldsw + 512], VgB + vo);
    }

    bool diag = (kt == qt);

    // S^T = K Q^T : lane(qd,ln) reg r holds (q=w*16+ln, t=mi*16+qd*4+r)
    f32x4 s[4] = {z, z, z, z};
#pragma unroll
    for (int mi = 0; mi < 4; ++mi) {
      if (diag && mi > w) continue;
#pragma unroll
      for (int kk = 0; kk < 2; ++kk) {
        frag8 ak = *(const frag8*)&Ks[cb + swi(mi * 16 + ln, 4 * kk + qd)];
        s[mi] = mfma_bf16(ak, qf[kk], s[mi]);
      }
    }

    // fixed-max softmax: p = exp2(s), packed to bf16x2 dwords in registers
    u32 pk[4][2];
#pragma unroll
    for (int mi = 0; mi < 4; ++mi) {
      if (diag && mi > w) { pk[mi][0] = 0u; pk[mi][1] = 0u; continue; }
      float p0 = __builtin_amdgcn_exp2f(s[mi][0]);
      float p1 = __builtin_amdgcn_exp2f(s[mi][1]);
      float p2 = __builtin_amdgcn_exp2f(s[mi][2]);
      float p3 = __builtin_amdgcn_exp2f(s[mi][3]);
      if (diag && mi == w) {  // t_local = qd*4+r vs q_local = ln
        p0 = (qd * 4 + 0 <= ln) ? p0 : 0.f;
        p1 = (qd * 4 + 1 <= ln) ? p1 : 0.f;
        p2 = (qd * 4 + 2 <= ln) ? p2 : 0.f;
        p3 = (qd * 4 + 3 <= ln) ? p3 : 0.f;
      }
      l_part += (p0 + p1) + (p2 + p3);
      u32 u0 = __builtin_bit_cast(u32, p0) + 0x8000u;
      u32 u1 = __builtin_bit_cast(u32, p1) + 0x8000u;
      u32 u2 = __builtin_bit_cast(u32, p2) + 0x8000u;
      u32 u3 = __builtin_bit_cast(u32, p3) + 0x8000u;
      pk[mi][0] = __builtin_amdgcn_perm(u1, u0, 0x07060302u);
      pk[mi][1] = __builtin_amdgcn_perm(u3, u2, 0x07060302u);
    }

    // O^T += V^T P^T; P B-frag built by cross-lane bpermute (no LDS)
    // target lane(qd,ln) needs q=w*16+ln (own column group), t=kk*32+qd*8+j:
    //   mi = 2kk + (qd>>1), source quad = (2qd+g)&3, dwords r-pairs of pk[mi]
#pragma unroll
    for (int kk = 0; kk < 2; ++kk) {
      if (diag && kk == 1 && w < 2) continue;  // t>=32 fully masked for band
      u32 a0 = __builtin_amdgcn_ds_bpermute(idxg0, (int)pk[2 * kk][0]);
      u32 a1 = __builtin_amdgcn_ds_bpermute(idxg0, (int)pk[2 * kk][1]);
      u32 a2 = __builtin_amdgcn_ds_bpermute(idxg1, (int)pk[2 * kk][0]);
      u32 a3 = __builtin_amdgcn_ds_bpermute(idxg1, (int)pk[2 * kk][1]);
      u32 c0 = __builtin_amdgcn_ds_bpermute(idxg0, (int)pk[2 * kk + 1][0]);
      u32 c1 = __builtin_amdgcn_ds_bpermute(idxg0, (int)pk[2 * kk + 1][1]);
      u32 c2 = __builtin_amdgcn_ds_bpermute(idxg1, (int)pk[2 * kk + 1][0]);
      u32 c3 = __builtin_amdgcn_ds_bpermute(idxg1, (int)pk[2 * kk + 1][1]);
      bool hi = qd >= 2;
      uint4 bpv;
      bpv.x = hi ? c0 : a0;
      bpv.y = hi ? c1 : a1;
      bpv.z = hi ? c2 : a2;
      bpv.w = hi ? c3 : a3;
      frag8 bp = __builtin_bit_cast(frag8, bpv);
#pragma unroll
      for (int mi = 0; mi < 4; ++mi) {
        frag8 av = *(const frag8*)&Vs[cb + swi(mi * 16 + ln, 4 * kk + qd)];
        o_acc[mi] = mfma_bf16(av, bp, o_acc[mi]);
      }
    }
  }

  // l reduction across quad groups (same q = ln in all quads)
  l_part += __shfl_xor(l_part, 16);
  l_part += __shfl_xor(l_part, 32);
  float rl = 1.0f / l_part;

#pragma unroll
  for (int mi = 0; mi < 4; ++mi) {
    ushort4 ov;
    ov.x = f2bf(o_acc[mi][0] * rl);
    ov.y = f2bf(o_acc[mi][1] * rl);
    ov.z = f2bf(o_acc[mi][2] * rl);
    ov.w = f2bf(o_acc[mi][3] * rl);
    *(ushort4*)&O[(size_t)(b * TT + q0 + w * 16 + ln) * DM + h * 64 + mi * 16 + qd * 4] = ov;
  }
}

extern "C" void kernel_launch(void* const* d_in, const int* in_sizes, int n_in,
                              void* d_out, int out_size, void* d_ws, size_t ws_size,
                              hipStream_t stream) {
  const float* x  = (const float*)d_in[0];
  const float* Wq = (const float*)d_in[1];
  const float* bq = (const float*)d_in[2];
  const float* Wk = (const float*)d_in[3];
  const float* bk = (const float*)d_in[4];
  const float* Wv = (const float*)d_in[5];
  const float* bv = (const float*)d_in[6];
  const float* Wo = (const float*)d_in[7];
  const float* bo = (const float*)d_in[8];

  char* ws = (char*)d_ws;
  const size_t MB = 1ull << 20;
  u16* xbf  = (u16*)(ws + 0);         // 8 MB  (4096 x 1024)
  u16* Wcat = (u16*)(ws + 8 * MB);    // 6 MB  (3072 x 1024: Wq^T|Wk^T|Wv^T)
  u16* Wot  = (u16*)(ws + 14 * MB);   // 2 MB
  u16* QKb  = (u16*)(ws + 16 * MB);   // 16 MB (4096 x 2048)
  u16* Vbb  = (u16*)(ws + 32 * MB);   // 8 MB  (4096 x 1024)
  u16* Vtb  = (u16*)(ws + 40 * MB);   // 8 MB  (32 x 64 x 2048)
  u16* Ob   = (u16*)(ws + 48 * MB);   // 8 MB

  cvt_x_kernel<<<4096, 256, 0, stream>>>(x, xbf);
  transpose_w_kernel<<<dim3(16, 16, 4), 256, 0, stream>>>(
      Wq, Wk, Wv, Wo, Wcat, Wcat + 1024 * 1024, Wcat + 2 * 1024 * 1024, Wot);
  gemm_qkv_kernel<<<dim3(24, 32), 256, 0, stream>>>(
      xbf, Wcat, bq, bk, bv, QKb, Vbb);
  transpose_v_kernel<<<dim3(32, 32), 256, 0, stream>>>(Vbb, Vtb);
  flash5_kernel<<<dim3(32, 32), 256, 0, stream>>>(QKb, Vtb, Ob);
  gemm_out_kernel<<<dim3(16, 32), 256, 0, stream>>>(Ob, Wot, bo, (float*)d_out);
}

// Round 6
// 220.353 us; speedup vs baseline: 1.0235x; 1.0235x over previous
//
#include <hip/hip_runtime.h>

typedef unsigned short u16;
typedef unsigned int u32;

#define DM 1024
#define NH 16
#define DH 64
#define BB 2
#define TT 2048

// Q pre-scale: (1/sqrt(64)) * log2(e)
#define SCLQ 0.18033688f

using frag8  = __attribute__((ext_vector_type(8))) short;
using frag4  = __attribute__((ext_vector_type(4))) short;
using bf16x8 = __attribute__((ext_vector_type(8))) __bf16;
using f32x4  = __attribute__((ext_vector_type(4))) float;

__device__ inline u16 f2bf(float f) {
  union { float f; u32 u; } v; v.f = f;
  u32 r = v.u + 0x7fffu + ((v.u >> 16) & 1u);
  return (u16)(r >> 16);
}

__device__ inline f32x4 mfma_bf16(frag8 a, frag8 b, f32x4 c) {
  return __builtin_amdgcn_mfma_f32_16x16x32_bf16(
      __builtin_bit_cast(bf16x8, a), __builtin_bit_cast(bf16x8, b), c, 0, 0, 0);
}

// K=16 MFMA: B-operand layout (n=ln, k=qd*4+i) == C-layout of 16x16 -> P stays in regs
__device__ inline f32x4 mfma16_bf16(frag4 a, frag4 b, f32x4 c) {
  return __builtin_amdgcn_mfma_f32_16x16x16bf16_1k(a, b, c, 0, 0, 0);
}

// async global->LDS, 16B/lane; LDS dest = base + lane*16 (wave-uniform base)
__device__ inline void gld16(void* lds, const void* g) {
  __builtin_amdgcn_global_load_lds(
      (const __attribute__((address_space(1))) void*)g,
      (__attribute__((address_space(3))) void*)lds, 16, 0, 0);
}

// swizzled LDS index (u16 units) for 64-u16 rows: 8 chunks of 16B,
// stored chunk position = chunk ^ (row & 7)
__device__ inline int swi(int row, int chunk) {
  return row * 64 + ((chunk ^ (row & 7)) << 3);
}
// b64 variant: t = kq*16 + qd*4 (+i), content chunk = 2kq + (qd>>1), +4 u16 if qd odd
__device__ inline int vswi(int row, int kq, int qd) {
  int c = 2 * kq + (qd >> 1);
  return row * 64 + ((c ^ (row & 7)) << 3) + ((qd & 1) << 2);
}

// ---------- x -> bf16 ----------
__global__ __launch_bounds__(256) void cvt_x_kernel(const float* __restrict__ X,
                                                    u16* __restrict__ Y) {
  int i = blockIdx.x * 256 + threadIdx.x;
  float4 v = ((const float4*)X)[i];
  ushort4 o;
  o.x = f2bf(v.x); o.y = f2bf(v.y); o.z = f2bf(v.z); o.w = f2bf(v.w);
  ((ushort4*)Y)[i] = o;
}

// ---------- W (K,N) fp32 -> Wt (N,K) bf16, tiled ----------
__global__ __launch_bounds__(256) void transpose_w_kernel(
    const float* __restrict__ W0, const float* __restrict__ W1,
    const float* __restrict__ W2, const float* __restrict__ W3,
    u16* __restrict__ O0, u16* __restrict__ O1,
    u16* __restrict__ O2, u16* __restrict__ O3) {
  const float* W; u16* Ot;
  switch (blockIdx.z) {
    case 0: W = W0; Ot = O0; break;
    case 1: W = W1; Ot = O1; break;
    case 2: W = W2; Ot = O2; break;
    default: W = W3; Ot = O3; break;
  }
  __shared__ u16 Ls[64][72];
  int tid = threadIdx.x;
  int n0 = blockIdx.x * 64;
  int k0 = blockIdx.y * 64;
#pragma unroll
  for (int p = 0; p < 4; ++p) {
    int id = tid + p * 256;
    int row = id >> 4;
    int c4 = (id & 15) * 4;
    float4 v = *(const float4*)&W[(size_t)(k0 + row) * DM + n0 + c4];
    ushort4 o; o.x = f2bf(v.x); o.y = f2bf(v.y); o.z = f2bf(v.z); o.w = f2bf(v.w);
    *(ushort4*)&Ls[row][c4] = o;
  }
  __syncthreads();
#pragma unroll
  for (int p = 0; p < 4; ++p) {
    int id = tid + p * 256;
    int row = id >> 4;
    int c4 = (id & 15) * 4;
    ushort4 o;
    o.x = Ls[c4 + 0][row]; o.y = Ls[c4 + 1][row];
    o.z = Ls[c4 + 2][row]; o.w = Ls[c4 + 3][row];
    *(ushort4*)&Ot[(size_t)(n0 + row) * DM + k0 + c4] = o;
  }
}

// ---------- QKV GEMM (double-buffered, 1 barrier/iter, swizzled LDS) ----------
__global__ __launch_bounds__(256, 3) void gemm_qkv_kernel(
    const u16* __restrict__ A, const u16* __restrict__ Bt,
    const float* __restrict__ b0, const float* __restrict__ b1,
    const float* __restrict__ b2,
    u16* __restrict__ QK, u16* __restrict__ Vb) {
  constexpr int K = 1024;
  __shared__ u16 As[2][4096];
  __shared__ u16 Bs[2][4096];
  int tid = threadIdx.x;
  int lane = tid & 63, w = tid >> 6;
  int qd = lane >> 4, ln = lane & 15;
  int wm = (w & 1) * 64, wn = (w >> 1) * 64;
  int m0 = blockIdx.y * 128, n0 = blockIdx.x * 128;
  f32x4 z = {0.f, 0.f, 0.f, 0.f};
  f32x4 acc[4][4];
#pragma unroll
  for (int mi = 0; mi < 4; ++mi)
#pragma unroll
    for (int ni = 0; ni < 4; ++ni) acc[mi][ni] = z;

  int csw = ((lane & 3) ^ ((lane >> 2) & 3)) * 8;
  const u16* ga = A + (size_t)(m0 + w * 32 + (lane >> 2)) * K + csw;
  const u16* gb = Bt + (size_t)(n0 + w * 32 + (lane >> 2)) * K + csw;

  gld16(&As[0][w * 1024],       ga);
  gld16(&As[0][w * 1024 + 512], ga + 16 * K);
  gld16(&Bs[0][w * 1024],       gb);
  gld16(&Bs[0][w * 1024 + 512], gb + 16 * K);

  int fsw = (qd ^ (ln & 3)) * 8;
  for (int k0 = 0; k0 < K; k0 += 32) {
    int cur = (k0 >> 5) & 1;
    __syncthreads();
    if (k0 + 32 < K) {
      int nb = cur ^ 1;
      gld16(&As[nb][w * 1024],       ga + k0 + 32);
      gld16(&As[nb][w * 1024 + 512], ga + k0 + 32 + 16 * K);
      gld16(&Bs[nb][w * 1024],       gb + k0 + 32);
      gld16(&Bs[nb][w * 1024 + 512], gb + k0 + 32 + 16 * K);
    }
    frag8 af[4], bfr[4];
#pragma unroll
    for (int mi = 0; mi < 4; ++mi)
      af[mi] = *(const frag8*)&As[cur][(wm + mi * 16 + ln) * 32 + fsw];
#pragma unroll
    for (int ni = 0; ni < 4; ++ni)
      bfr[ni] = *(const frag8*)&Bs[cur][(wn + ni * 16 + ln) * 32 + fsw];
#pragma unroll
    for (int mi = 0; mi < 4; ++mi)
#pragma unroll
      for (int ni = 0; ni < 4; ++ni)
        acc[mi][ni] = mfma_bf16(af[mi], bfr[ni], acc[mi][ni]);
  }

#pragma unroll
  for (int ni = 0; ni < 4; ++ni) {
    int col = n0 + wn + ni * 16 + ln;
    if (col < 2048) {
      bool isq = col < 1024;
      float bias = isq ? b0[col] : b1[col - 1024];
#pragma unroll
      for (int mi = 0; mi < 4; ++mi) {
        int row = m0 + wm + mi * 16 + qd * 4;
#pragma unroll
        for (int r = 0; r < 4; ++r) {
          float v = acc[mi][ni][r] + bias;
          if (isq) v *= SCLQ;
          QK[(size_t)(row + r) * 2048 + col] = f2bf(v);
        }
      }
    } else {
      int c2 = col - 2048;
      float bias = b2[c2];
#pragma unroll
      for (int mi = 0; mi < 4; ++mi) {
        int row = m0 + wm + mi * 16 + qd * 4;
#pragma unroll
        for (int r = 0; r < 4; ++r)
          Vb[(size_t)(row + r) * 1024 + c2] = f2bf(acc[mi][ni][r] + bias);
      }
    }
  }
}

// ---------- out-proj GEMM (double-buffered, swizzled): 128x64, f32 out ----------
__global__ __launch_bounds__(256) void gemm_out_kernel(
    const u16* __restrict__ A, const u16* __restrict__ Bt,
    const float* __restrict__ b0, float* __restrict__ Cf) {
  constexpr int K = 1024;
  __shared__ u16 As[2][4096];
  __shared__ u16 Bs[2][2048];
  int tid = threadIdx.x;
  int lane = tid & 63, w = tid >> 6;
  int qd = lane >> 4, ln = lane & 15;
  int m0 = blockIdx.y * 128, n0 = blockIdx.x * 64;
  f32x4 z = {0.f, 0.f, 0.f, 0.f};
  f32x4 acc[2][4];
#pragma unroll
  for (int mi = 0; mi < 2; ++mi)
#pragma unroll
    for (int ni = 0; ni < 4; ++ni) acc[mi][ni] = z;

  int csw = ((lane & 3) ^ ((lane >> 2) & 3)) * 8;
  const u16* ga = A + (size_t)(m0 + w * 32 + (lane >> 2)) * K + csw;
  const u16* gb = Bt + (size_t)(n0 + w * 16 + (lane >> 2)) * K + csw;

  gld16(&As[0][w * 1024],       ga);
  gld16(&As[0][w * 1024 + 512], ga + 16 * K);
  gld16(&Bs[0][w * 512],        gb);

  int fsw = (qd ^ (ln & 3)) * 8;
  for (int k0 = 0; k0 < K; k0 += 32) {
    int cur = (k0 >> 5) & 1;
    __syncthreads();
    if (k0 + 32 < K) {
      int nb = cur ^ 1;
      gld16(&As[nb][w * 1024],       ga + k0 + 32);
      gld16(&As[nb][w * 1024 + 512], ga + k0 + 32 + 16 * K);
      gld16(&Bs[nb][w * 512],        gb + k0 + 32);
    }
    frag8 af[2], bfr[4];
#pragma unroll
    for (int mi = 0; mi < 2; ++mi)
      af[mi] = *(const frag8*)&As[cur][(w * 32 + mi * 16 + ln) * 32 + fsw];
#pragma unroll
    for (int ni = 0; ni < 4; ++ni)
      bfr[ni] = *(const frag8*)&Bs[cur][(ni * 16 + ln) * 32 + fsw];
#pragma unroll
    for (int mi = 0; mi < 2; ++mi)
#pragma unroll
      for (int ni = 0; ni < 4; ++ni)
        acc[mi][ni] = mfma_bf16(af[mi], bfr[ni], acc[mi][ni]);
  }

#pragma unroll
  for (int ni = 0; ni < 4; ++ni) {
    int col = n0 + ni * 16 + ln;
    float bias = b0[col];
#pragma unroll
    for (int mi = 0; mi < 2; ++mi) {
      int row = m0 + w * 32 + mi * 16 + qd * 4;
#pragma unroll
      for (int r = 0; r < 4; ++r)
        Cf[(size_t)(row + r) * 1024 + col] = acc[mi][ni][r] + bias;
    }
  }
}

// ---------- V (B,T,D) bf16 -> Vt (B,H,DH,T) bf16, tiled ----------
__global__ __launch_bounds__(256) void transpose_v_kernel(const u16* __restrict__ V,
                                                          u16* __restrict__ Vt) {
  int bh = blockIdx.y;
  int b = bh >> 4, h = bh & 15;
  int t0 = blockIdx.x * 64;
  __shared__ u16 Ls[64][72];
  int tid = threadIdx.x;
#pragma unroll
  for (int p = 0; p < 2; ++p) {
    int id = tid + p * 256;
    int row = id >> 3, seg = id & 7;
    *(uint4*)&Ls[row][seg * 8] =
        *(const uint4*)&V[(size_t)(b * TT + t0 + row) * DM + h * DH + seg * 8];
  }
  __syncthreads();
#pragma unroll
  for (int p = 0; p < 2; ++p) {
    int id = tid + p * 256;
    int d = id >> 3, seg = id & 7;
    union { u16 s[8]; uint4 v; } tmp;
#pragma unroll
    for (int j = 0; j < 8; ++j) tmp.s[j] = Ls[seg * 8 + j][d];
    *(uint4*)&Vt[(size_t)(bh * DH + d) * TT + t0 + seg * 8] = tmp.v;
  }
}

// ---------- flash v6: paired q-tiles + K=16 PV (P never leaves registers) ----------
// QK: [B*T][2048] bf16 (Q pre-scaled, K). Vt: [B*H][DH][TT]. O: [B*T][1024] bf16.
__global__ __launch_bounds__(256, 4) void flash6_kernel(const u16* __restrict__ QK,
                                                        const u16* __restrict__ Vt,
                                                        u16* __restrict__ O) {
  int pj = blockIdx.x;            // 0..15
  int bh = blockIdx.y;
  int b = bh >> 4, h = bh & 15;
  int qtA = pj, qtB = 31 - pj;    // diags never coincide
  int q0A = qtA * 64, q0B = qtB * 64;
  __shared__ u16 Ks[2 * 4096];
  __shared__ u16 Vs[2 * 4096];
  int tid = threadIdx.x;
  int lane = tid & 63, w = tid >> 6;
  int qd = lane >> 4, ln = lane & 15;

  // Q fragments (B-operand x32: n=ln -> q, k=qd*8+j -> d); Q pre-scaled by SCLQ
  frag8 qfA[2], qfB[2];
#pragma unroll
  for (int kk = 0; kk < 2; ++kk) {
    qfA[kk] = *(const frag8*)&QK[(size_t)(b * TT + q0A + w * 16 + ln) * 2048 +
                                 h * 64 + kk * 32 + qd * 8];
    qfB[kk] = *(const frag8*)&QK[(size_t)(b * TT + q0B + w * 16 + ln) * 2048 +
                                 h * 64 + kk * 32 + qd * 8];
  }

  // swizzled global_load_lds staging
  int lr = lane >> 3, lc = (lane & 7) ^ lr;
  const u16* KgA = &QK[(size_t)(b * TT + w * 16 + lr) * 2048 + 1024 + h * 64 + lc * 8];
  const u16* KgB = KgA + 8 * 2048;
  const u16* VgA = &Vt[(size_t)(bh * 64 + w * 16 + lr) * 2048 + lc * 8];
  const u16* VgB = VgA + 8 * 2048;
  int ldsw = w * 1024;

  int nkt = qtB + 1;
  gld16(&Ks[ldsw],       KgA);
  gld16(&Ks[ldsw + 512], KgB);
  gld16(&Vs[ldsw],       VgA);
  gld16(&Vs[ldsw + 512], VgB);

  float lA = 0.f, lB = 0.f;
  f32x4 z = {0.f, 0.f, 0.f, 0.f};
  f32x4 oA[4] = {z, z, z, z};
  f32x4 oB[4] = {z, z, z, z};

  for (int kt = 0; kt < nkt; ++kt) {
    int cur = kt & 1;
    int cb = cur * 4096;
    __syncthreads();

    if (kt + 1 < nkt) {
      int nb = (cur ^ 1) * 4096;
      size_t ko = (size_t)(kt + 1) * 64 * 2048;
      int vo = (kt + 1) * 64;
      gld16(&Ks[nb + ldsw],       KgA + ko);
      gld16(&Ks[nb + ldsw + 512], KgB + ko);
      gld16(&Vs[nb + ldsw],       VgA + vo);
      gld16(&Vs[nb + ldsw + 512], VgB + vo);
    }

    bool actA  = (kt <= qtA);
    bool diagA = (kt == qtA);
    bool diagB = (kt == qtB);

    // S^T = K Q^T, shared K fragment loads
    f32x4 sA[4] = {z, z, z, z};
    f32x4 sB[4] = {z, z, z, z};
#pragma unroll
    for (int mi = 0; mi < 4; ++mi) {
      bool skipB = diagB && (mi > w);
      bool doA = actA && !(diagA && (mi > w));
      if (skipB && !doA) continue;
#pragma unroll
      for (int kk = 0; kk < 2; ++kk) {
        frag8 ak = *(const frag8*)&Ks[cb + swi(mi * 16 + ln, 4 * kk + qd)];
        if (!skipB) sB[mi] = mfma_bf16(ak, qfB[kk], sB[mi]);
        if (doA)    sA[mi] = mfma_bf16(ak, qfA[kk], sA[mi]);
      }
    }

    // fixed-max softmax: p = exp2(s); packed bf16 pairs ARE the K=16 B-fragment
    u32 pkA[4][2], pkB[4][2];
    auto softmax_pack = [&](f32x4* s, bool diag, u32 (*pk)[2], float& lacc) {
#pragma unroll
      for (int mi = 0; mi < 4; ++mi) {
        if (diag && mi > w) { pk[mi][0] = 0u; pk[mi][1] = 0u; continue; }
        float p0 = __builtin_amdgcn_exp2f(s[mi][0]);
        float p1 = __builtin_amdgcn_exp2f(s[mi][1]);
        float p2 = __builtin_amdgcn_exp2f(s[mi][2]);
        float p3 = __builtin_amdgcn_exp2f(s[mi][3]);
        if (diag && mi == w) {  // t_local = qd*4+r vs q_local = ln
          p0 = (qd * 4 + 0 <= ln) ? p0 : 0.f;
          p1 = (qd * 4 + 1 <= ln) ? p1 : 0.f;
          p2 = (qd * 4 + 2 <= ln) ? p2 : 0.f;
          p3 = (qd * 4 + 3 <= ln) ? p3 : 0.f;
        }
        lacc += (p0 + p1) + (p2 + p3);
        u32 u0 = __builtin_bit_cast(u32, p0) + 0x8000u;
        u32 u1 = __builtin_bit_cast(u32, p1) + 0x8000u;
        u32 u2 = __builtin_bit_cast(u32, p2) + 0x8000u;
        u32 u3 = __builtin_bit_cast(u32, p3) + 0x8000u;
        pk[mi][0] = __builtin_amdgcn_perm(u1, u0, 0x07060302u);
        pk[mi][1] = __builtin_amdgcn_perm(u3, u2, 0x07060302u);
      }
    };
    softmax_pack(sB, diagB, pkB, lB);
    if (actA) softmax_pack(sA, diagA, pkA, lA);

    // O^T += V^T P^T via K=16 MFMA; A = V^T b64 frags (shared), B = pk in regs
#pragma unroll
    for (int kq = 0; kq < 4; ++kq) {
      bool skipB = diagB && (kq > w);
      bool doA = actA && !(diagA && (kq > w));
      if (skipB && !doA) continue;
      uint2 tb; tb.x = pkB[kq][0]; tb.y = pkB[kq][1];
      frag4 bpB = __builtin_bit_cast(frag4, tb);
      frag4 bpA;
      if (doA) { uint2 ta; ta.x = pkA[kq][0]; ta.y = pkA[kq][1];
                 bpA = __builtin_bit_cast(frag4, ta); }
#pragma unroll
      for (int di = 0; di < 4; ++di) {
        frag4 av = *(const frag4*)&Vs[cb + vswi(di * 16 + ln, kq, qd)];
        if (!skipB) oB[di] = mfma16_bf16(av, bpB, oB[di]);
        if (doA)    oA[di] = mfma16_bf16(av, bpA, oA[di]);
      }
    }
  }

  lA += __shfl_xor(lA, 16); lA += __shfl_xor(lA, 32);
  lB += __shfl_xor(lB, 16); lB += __shfl_xor(lB, 32);
  float rlA = 1.0f / lA, rlB = 1.0f / lB;

#pragma unroll
  for (int di = 0; di < 4; ++di) {
    ushort4 ov;
    ov.x = f2bf(oA[di][0] * rlA); ov.y = f2bf(oA[di][1] * rlA);
    ov.z = f2bf(oA[di][2] * rlA); ov.w = f2bf(oA[di][3] * rlA);
    *(ushort4*)&O[(size_t)(b * TT + q0A + w * 16 + ln) * DM + h * 64 + di * 16 + qd * 4] = ov;
    ov.x = f2bf(oB[di][0] * rlB); ov.y = f2bf(oB[di][1] * rlB);
    ov.z = f2bf(oB[di][2] * rlB); ov.w = f2bf(oB[di][3] * rlB);
    *(ushort4*)&O[(size_t)(b * TT + q0B + w * 16 + ln) * DM + h * 64 + di * 16 + qd * 4] = ov;
  }
}

extern "C" void kernel_launch(void* const* d_in, const int* in_sizes, int n_in,
                              void* d_out, int out_size, void* d_ws, size_t ws_size,
                              hipStream_t stream) {
  const float* x  = (const float*)d_in[0];
  const float* Wq = (const float*)d_in[1];
  const float* bq = (const float*)d_in[2];
  const float* Wk = (const float*)d_in[3];
  const float* bk = (const float*)d_in[4];
  const float* Wv = (const float*)d_in[5];
  const float* bv = (const float*)d_in[6];
  const float* Wo = (const float*)d_in[7];
  const float* bo = (const float*)d_in[8];

  char* ws = (char*)d_ws;
  const size_t MB = 1ull << 20;
  u16* xbf  = (u16*)(ws + 0);         // 8 MB  (4096 x 1024)
  u16* Wcat = (u16*)(ws + 8 * MB);    // 6 MB  (3072 x 1024: Wq^T|Wk^T|Wv^T)
  u16* Wot  = (u16*)(ws + 14 * MB);   // 2 MB
  u16* QKb  = (u16*)(ws + 16 * MB);   // 16 MB (4096 x 2048)
  u16* Vbb  = (u16*)(ws + 32 * MB);   // 8 MB  (4096 x 1024)
  u16* Vtb  = (u16*)(ws + 40 * MB);   // 8 MB  (32 x 64 x 2048)
  u16* Ob   = (u16*)(ws + 48 * MB);   // 8 MB

  cvt_x_kernel<<<4096, 256, 0, stream>>>(x, xbf);
  transpose_w_kernel<<<dim3(16, 16, 4), 256, 0, stream>>>(
      Wq, Wk, Wv, Wo, Wcat, Wcat + 1024 * 1024, Wcat + 2 * 1024 * 1024, Wot);
  gemm_qkv_kernel<<<dim3(24, 32), 256, 0, stream>>>(
      xbf, Wcat, bq, bk, bv, QKb, Vbb);
  transpose_v_kernel<<<dim3(32, 32), 256, 0, stream>>>(Vbb, Vtb);
  flash6_kernel<<<dim3(16, 32), 256, 0, stream>>>(QKb, Vtb, Ob);
  gemm_out_kernel<<<dim3(16, 32), 256, 0, stream>>>(Ob, Wot, bo, (float*)d_out);
}

// Round 7
// 218.112 us; speedup vs baseline: 1.0340x; 1.0103x over previous
//
#include <hip/hip_runtime.h>

typedef unsigned short u16;
typedef unsigned int u32;

#define DM 1024
#define NH 16
#define DH 64
#define BB 2
#define TT 2048

// Q pre-scale: (1/sqrt(64)) * log2(e)
#define SCLQ 0.18033688f

using frag8  = __attribute__((ext_vector_type(8))) short;
using bf16x8 = __attribute__((ext_vector_type(8))) __bf16;
using f32x4  = __attribute__((ext_vector_type(4))) float;

__device__ inline u16 f2bf(float f) {
  union { float f; u32 u; } v; v.f = f;
  u32 r = v.u + 0x7fffu + ((v.u >> 16) & 1u);
  return (u16)(r >> 16);
}

__device__ inline f32x4 mfma_bf16(frag8 a, frag8 b, f32x4 c) {
  return __builtin_amdgcn_mfma_f32_16x16x32_bf16(
      __builtin_bit_cast(bf16x8, a), __builtin_bit_cast(bf16x8, b), c, 0, 0, 0);
}

// async global->LDS, 16B/lane; LDS dest = base + lane*16 (wave-uniform base)
__device__ inline void gld16(void* lds, const void* g) {
  __builtin_amdgcn_global_load_lds(
      (const __attribute__((address_space(1))) void*)g,
      (__attribute__((address_space(3))) void*)lds, 16, 0, 0);
}

// swizzled LDS index (u16 units) for 64-u16 rows: 8 chunks of 16B,
// stored chunk position = chunk ^ (row & 7)
__device__ inline int swi(int row, int chunk) {
  return row * 64 + ((chunk ^ (row & 7)) << 3);
}

// ---------- x -> bf16 ----------
__global__ __launch_bounds__(256) void cvt_x_kernel(const float* __restrict__ X,
                                                    u16* __restrict__ Y) {
  int i = blockIdx.x * 256 + threadIdx.x;
  float4 v = ((const float4*)X)[i];
  ushort4 o;
  o.x = f2bf(v.x); o.y = f2bf(v.y); o.z = f2bf(v.z); o.w = f2bf(v.w);
  ((ushort4*)Y)[i] = o;
}

// ---------- W (K,N) fp32 -> Wt (N,K) bf16, tiled ----------
__global__ __launch_bounds__(256) void transpose_w_kernel(
    const float* __restrict__ W0, const float* __restrict__ W1,
    const float* __restrict__ W2, const float* __restrict__ W3,
    u16* __restrict__ O0, u16* __restrict__ O1,
    u16* __restrict__ O2, u16* __restrict__ O3) {
  const float* W; u16* Ot;
  switch (blockIdx.z) {
    case 0: W = W0; Ot = O0; break;
    case 1: W = W1; Ot = O1; break;
    case 2: W = W2; Ot = O2; break;
    default: W = W3; Ot = O3; break;
  }
  __shared__ u16 Ls[64][72];
  int tid = threadIdx.x;
  int n0 = blockIdx.x * 64;
  int k0 = blockIdx.y * 64;
#pragma unroll
  for (int p = 0; p < 4; ++p) {
    int id = tid + p * 256;
    int row = id >> 4;
    int c4 = (id & 15) * 4;
    float4 v = *(const float4*)&W[(size_t)(k0 + row) * DM + n0 + c4];
    ushort4 o; o.x = f2bf(v.x); o.y = f2bf(v.y); o.z = f2bf(v.z); o.w = f2bf(v.w);
    *(ushort4*)&Ls[row][c4] = o;
  }
  __syncthreads();
#pragma unroll
  for (int p = 0; p < 4; ++p) {
    int id = tid + p * 256;
    int row = id >> 4;
    int c4 = (id & 15) * 4;
    ushort4 o;
    o.x = Ls[c4 + 0][row]; o.y = Ls[c4 + 1][row];
    o.z = Ls[c4 + 2][row]; o.w = Ls[c4 + 3][row];
    *(ushort4*)&Ot[(size_t)(n0 + row) * DM + k0 + c4] = o;
  }
}

// ---------- QKV GEMM (double-buffered, 1 barrier/iter, swizzled LDS) ----------
__global__ __launch_bounds__(256, 3) void gemm_qkv_kernel(
    const u16* __restrict__ A, const u16* __restrict__ Bt,
    const float* __restrict__ b0, const float* __restrict__ b1,
    const float* __restrict__ b2,
    u16* __restrict__ QK, u16* __restrict__ Vb) {
  constexpr int K = 1024;
  __shared__ u16 As[2][4096];
  __shared__ u16 Bs[2][4096];
  int tid = threadIdx.x;
  int lane = tid & 63, w = tid >> 6;
  int qd = lane >> 4, ln = lane & 15;
  int wm = (w & 1) * 64, wn = (w >> 1) * 64;
  int m0 = blockIdx.y * 128, n0 = blockIdx.x * 128;
  f32x4 z = {0.f, 0.f, 0.f, 0.f};
  f32x4 acc[4][4];
#pragma unroll
  for (int mi = 0; mi < 4; ++mi)
#pragma unroll
    for (int ni = 0; ni < 4; ++ni) acc[mi][ni] = z;

  int csw = ((lane & 3) ^ ((lane >> 2) & 3)) * 8;
  const u16* ga = A + (size_t)(m0 + w * 32 + (lane >> 2)) * K + csw;
  const u16* gb = Bt + (size_t)(n0 + w * 32 + (lane >> 2)) * K + csw;

  gld16(&As[0][w * 1024],       ga);
  gld16(&As[0][w * 1024 + 512], ga + 16 * K);
  gld16(&Bs[0][w * 1024],       gb);
  gld16(&Bs[0][w * 1024 + 512], gb + 16 * K);

  int fsw = (qd ^ (ln & 3)) * 8;
  for (int k0 = 0; k0 < K; k0 += 32) {
    int cur = (k0 >> 5) & 1;
    __syncthreads();
    if (k0 + 32 < K) {
      int nb = cur ^ 1;
      gld16(&As[nb][w * 1024],       ga + k0 + 32);
      gld16(&As[nb][w * 1024 + 512], ga + k0 + 32 + 16 * K);
      gld16(&Bs[nb][w * 1024],       gb + k0 + 32);
      gld16(&Bs[nb][w * 1024 + 512], gb + k0 + 32 + 16 * K);
    }
    frag8 af[4], bfr[4];
#pragma unroll
    for (int mi = 0; mi < 4; ++mi)
      af[mi] = *(const frag8*)&As[cur][(wm + mi * 16 + ln) * 32 + fsw];
#pragma unroll
    for (int ni = 0; ni < 4; ++ni)
      bfr[ni] = *(const frag8*)&Bs[cur][(wn + ni * 16 + ln) * 32 + fsw];
#pragma unroll
    for (int mi = 0; mi < 4; ++mi)
#pragma unroll
      for (int ni = 0; ni < 4; ++ni)
        acc[mi][ni] = mfma_bf16(af[mi], bfr[ni], acc[mi][ni]);
  }

#pragma unroll
  for (int ni = 0; ni < 4; ++ni) {
    int col = n0 + wn + ni * 16 + ln;
    if (col < 2048) {
      bool isq = col < 1024;
      float bias = isq ? b0[col] : b1[col - 1024];
#pragma unroll
      for (int mi = 0; mi < 4; ++mi) {
        int row = m0 + wm + mi * 16 + qd * 4;
#pragma unroll
        for (int r = 0; r < 4; ++r) {
          float v = acc[mi][ni][r] + bias;
          if (isq) v *= SCLQ;
          QK[(size_t)(row + r) * 2048 + col] = f2bf(v);
        }
      }
    } else {
      int c2 = col - 2048;
      float bias = b2[c2];
#pragma unroll
      for (int mi = 0; mi < 4; ++mi) {
        int row = m0 + wm + mi * 16 + qd * 4;
#pragma unroll
        for (int r = 0; r < 4; ++r)
          Vb[(size_t)(row + r) * 1024 + c2] = f2bf(acc[mi][ni][r] + bias);
      }
    }
  }
}

// ---------- out-proj GEMM (double-buffered, swizzled): 128x64, f32 out ----------
__global__ __launch_bounds__(256) void gemm_out_kernel(
    const u16* __restrict__ A, const u16* __restrict__ Bt,
    const float* __restrict__ b0, float* __restrict__ Cf) {
  constexpr int K = 1024;
  __shared__ u16 As[2][4096];
  __shared__ u16 Bs[2][2048];
  int tid = threadIdx.x;
  int lane = tid & 63, w = tid >> 6;
  int qd = lane >> 4, ln = lane & 15;
  int m0 = blockIdx.y * 128, n0 = blockIdx.x * 64;
  f32x4 z = {0.f, 0.f, 0.f, 0.f};
  f32x4 acc[2][4];
#pragma unroll
  for (int mi = 0; mi < 2; ++mi)
#pragma unroll
    for (int ni = 0; ni < 4; ++ni) acc[mi][ni] = z;

  int csw = ((lane & 3) ^ ((lane >> 2) & 3)) * 8;
  const u16* ga = A + (size_t)(m0 + w * 32 + (lane >> 2)) * K + csw;
  const u16* gb = Bt + (size_t)(n0 + w * 16 + (lane >> 2)) * K + csw;

  gld16(&As[0][w * 1024],       ga);
  gld16(&As[0][w * 1024 + 512], ga + 16 * K);
  gld16(&Bs[0][w * 512],        gb);

  int fsw = (qd ^ (ln & 3)) * 8;
  for (int k0 = 0; k0 < K; k0 += 32) {
    int cur = (k0 >> 5) & 1;
    __syncthreads();
    if (k0 + 32 < K) {
      int nb = cur ^ 1;
      gld16(&As[nb][w * 1024],       ga + k0 + 32);
      gld16(&As[nb][w * 1024 + 512], ga + k0 + 32 + 16 * K);
      gld16(&Bs[nb][w * 512],        gb + k0 + 32);
    }
    frag8 af[2], bfr[4];
#pragma unroll
    for (int mi = 0; mi < 2; ++mi)
      af[mi] = *(const frag8*)&As[cur][(w * 32 + mi * 16 + ln) * 32 + fsw];
#pragma unroll
    for (int ni = 0; ni < 4; ++ni)
      bfr[ni] = *(const frag8*)&Bs[cur][(ni * 16 + ln) * 32 + fsw];
#pragma unroll
    for (int mi = 0; mi < 2; ++mi)
#pragma unroll
      for (int ni = 0; ni < 4; ++ni)
        acc[mi][ni] = mfma_bf16(af[mi], bfr[ni], acc[mi][ni]);
  }

#pragma unroll
  for (int ni = 0; ni < 4; ++ni) {
    int col = n0 + ni * 16 + ln;
    float bias = b0[col];
#pragma unroll
    for (int mi = 0; mi < 2; ++mi) {
      int row = m0 + w * 32 + mi * 16 + qd * 4;
#pragma unroll
      for (int r = 0; r < 4; ++r)
        Cf[(size_t)(row + r) * 1024 + col] = acc[mi][ni][r] + bias;
    }
  }
}

// ---------- V (B,T,D) bf16 -> Vt (B,H,DH,T) bf16, tiled ----------
__global__ __launch_bounds__(256) void transpose_v_kernel(const u16* __restrict__ V,
                                                          u16* __restrict__ Vt) {
  int bh = blockIdx.y;
  int b = bh >> 4, h = bh & 15;
  int t0 = blockIdx.x * 64;
  __shared__ u16 Ls[64][72];
  int tid = threadIdx.x;
#pragma unroll
  for (int p = 0; p < 2; ++p) {
    int id = tid + p * 256;
    int row = id >> 3, seg = id & 7;
    *(uint4*)&Ls[row][seg * 8] =
        *(const uint4*)&V[(size_t)(b * TT + t0 + row) * DM + h * DH + seg * 8];
  }
  __syncthreads();
#pragma unroll
  for (int p = 0; p < 2; ++p) {
    int id = tid + p * 256;
    int d = id >> 3, seg = id & 7;
    union { u16 s[8]; uint4 v; } tmp;
#pragma unroll
    for (int j = 0; j < 8; ++j) tmp.s[j] = Ls[seg * 8 + j][d];
    *(uint4*)&Vt[(size_t)(bh * DH + d) * TT + t0 + seg * 8] = tmp.v;
  }
}

// ---------- flash v7: paired q-tiles, software-pipelined S(kt+1)/PV(kt),
//            triple-ring K/V staging, wave-private single-buffer Ps ----------
// QK: [B*T][2048] bf16 (Q pre-scaled, K). Vt: [B*H][DH][TT]. O: [B*T][1024] bf16.
__global__ __launch_bounds__(256, 2) void flash7_kernel(const u16* __restrict__ QK,
                                                        const u16* __restrict__ Vt,
                                                        u16* __restrict__ O) {
  int pj = blockIdx.x;            // 0..15
  int bh = blockIdx.y;
  int b = bh >> 4, h = bh & 15;
  int qtA = pj, qtB = 31 - pj;    // diags never coincide; uniform 33 tiles/block
  int q0A = qtA * 64, q0B = qtB * 64;
  __shared__ u16 Ks[3 * 4096];
  __shared__ u16 Vs[3 * 4096];
  __shared__ u16 PsA[4096];       // wave-private rows -> single buffer is safe
  __shared__ u16 PsB[4096];
  int tid = threadIdx.x;
  int lane = tid & 63, w = tid >> 6;
  int qd = lane >> 4, ln = lane & 15;

  // Q fragments (B-operand: n=ln -> q, k=qd*8+j -> d); Q pre-scaled by SCLQ
  frag8 qfA[2], qfB[2];
#pragma unroll
  for (int kk = 0; kk < 2; ++kk) {
    qfA[kk] = *(const frag8*)&QK[(size_t)(b * TT + q0A + w * 16 + ln) * 2048 +
                                 h * 64 + kk * 32 + qd * 8];
    qfB[kk] = *(const frag8*)&QK[(size_t)(b * TT + q0B + w * 16 + ln) * 2048 +
                                 h * 64 + kk * 32 + qd * 8];
  }

  // swizzled global_load_lds staging
  int lr = lane >> 3, lc = (lane & 7) ^ lr;
  const u16* KgA = &QK[(size_t)(b * TT + w * 16 + lr) * 2048 + 1024 + h * 64 + lc * 8];
  const u16* KgB = KgA + 8 * 2048;
  const u16* VgA = &Vt[(size_t)(bh * 64 + w * 16 + lr) * 2048 + lc * 8];
  const u16* VgB = VgA + 8 * 2048;
  int ldsw = w * 1024;

  int nkt = qtB + 1;  // >= 17

  float lA = 0.f, lB = 0.f;
  f32x4 z = {0.f, 0.f, 0.f, 0.f};
  f32x4 oA[4] = {z, z, z, z};
  f32x4 oB[4] = {z, z, z, z};

  // S^T = K Q^T for tile j from K ring slot; shared K fragment loads
  auto compute_S = [&](int j, int slot, f32x4* sA, f32x4* sB) {
    int cb = slot * 4096;
    bool actA_ = (j <= qtA), diagA_ = (j == qtA), diagB_ = (j == qtB);
#pragma unroll
    for (int mi = 0; mi < 4; ++mi) {
      bool skipB = diagB_ && (mi > w);
      bool doA = actA_ && !(diagA_ && (mi > w));
      if (skipB && !doA) continue;
#pragma unroll
      for (int kk = 0; kk < 2; ++kk) {
        frag8 ak = *(const frag8*)&Ks[cb + swi(mi * 16 + ln, 4 * kk + qd)];
        if (!skipB) sB[mi] = mfma_bf16(ak, qfB[kk], sB[mi]);
        if (doA)    sA[mi] = mfma_bf16(ak, qfA[kk], sA[mi]);
      }
    }
  };

  // fixed-max softmax for tile j: p = exp2(s); pack bf16, store P^T to wave rows
  auto softmax_store = [&](f32x4* s, bool act, bool diag, u16* Ps, float& lacc) {
    if (!act) return;
#pragma unroll
    for (int mi = 0; mi < 4; ++mi) {
      int pb = swi(w * 16 + ln, 2 * mi + (qd >> 1)) + (qd & 1) * 4;
      if (diag && mi > w) {
        uint2 zz; zz.x = 0u; zz.y = 0u;
        *(uint2*)&Ps[pb] = zz;
        continue;
      }
      float p0 = __builtin_amdgcn_exp2f(s[mi][0]);
      float p1 = __builtin_amdgcn_exp2f(s[mi][1]);
      float p2 = __builtin_amdgcn_exp2f(s[mi][2]);
      float p3 = __builtin_amdgcn_exp2f(s[mi][3]);
      if (diag && mi == w) {  // t_local = qd*4+r vs q_local = ln
        p0 = (qd * 4 + 0 <= ln) ? p0 : 0.f;
        p1 = (qd * 4 + 1 <= ln) ? p1 : 0.f;
        p2 = (qd * 4 + 2 <= ln) ? p2 : 0.f;
        p3 = (qd * 4 + 3 <= ln) ? p3 : 0.f;
      }
      lacc += (p0 + p1) + (p2 + p3);
      u32 u0 = __builtin_bit_cast(u32, p0) + 0x8000u;
      u32 u1 = __builtin_bit_cast(u32, p1) + 0x8000u;
      u32 u2 = __builtin_bit_cast(u32, p2) + 0x8000u;
      u32 u3 = __builtin_bit_cast(u32, p3) + 0x8000u;
      uint2 pk;
      pk.x = __builtin_amdgcn_perm(u1, u0, 0x07060302u);
      pk.y = __builtin_amdgcn_perm(u3, u2, 0x07060302u);
      *(uint2*)&Ps[pb] = pk;
    }
  };

  // prologue: stage tiles 0 (slot0) and 1 (slot1)
  gld16(&Ks[ldsw],            KgA);
  gld16(&Ks[ldsw + 512],      KgB);
  gld16(&Vs[ldsw],            VgA);
  gld16(&Vs[ldsw + 512],      VgB);
  {
    size_t ko = (size_t)64 * 2048;
    gld16(&Ks[4096 + ldsw],       KgA + ko);
    gld16(&Ks[4096 + ldsw + 512], KgB + ko);
    gld16(&Vs[4096 + ldsw],       VgA + 64);
    gld16(&Vs[4096 + ldsw + 512], VgB + 64);
  }
  __syncthreads();

  // S(0) + P(0)
  {
    f32x4 sA[4] = {z, z, z, z};
    f32x4 sB[4] = {z, z, z, z};
    compute_S(0, 0, sA, sB);
    softmax_store(sA, true, qtA == 0, PsA, lA);
    softmax_store(sB, true, false, PsB, lB);
  }

  for (int kt = 0; kt < nkt; ++kt) {
    // stage tile kt+2 into ring slot (kt+2)%3 (freed two barriers ago)
    if (kt + 2 < nkt) {
      int ns = ((kt + 2) % 3) * 4096;
      size_t ko = (size_t)(kt + 2) * 64 * 2048;
      int vo = (kt + 2) * 64;
      gld16(&Ks[ns + ldsw],       KgA + ko);
      gld16(&Ks[ns + ldsw + 512], KgB + ko);
      gld16(&Vs[ns + ldsw],       VgA + vo);
      gld16(&Vs[ns + ldsw + 512], VgB + vo);
    }

    int j = kt + 1;
    bool hasNext = (j < nkt);

    // S(kt+1): independent of PV(kt) -> two MFMA streams interleave
    f32x4 sA[4] = {z, z, z, z};
    f32x4 sB[4] = {z, z, z, z};
    if (hasNext) compute_S(j, j % 3, sA, sB);

    // PV(kt): reads Ps written last iter (wave-private; reads precede rewrites)
    {
      int cb = (kt % 3) * 4096;
      bool diagB_pv = (kt == qtB);
      bool actA_pv = (kt <= qtA);
#pragma unroll
      for (int kk = 0; kk < 2; ++kk) {
        if (diagB_pv && kk == 1 && w < 2) continue;  // fully masked; A inactive here
        frag8 bpB = *(const frag8*)&PsB[swi(w * 16 + ln, 4 * kk + qd)];
        frag8 bpA;
        if (actA_pv) bpA = *(const frag8*)&PsA[swi(w * 16 + ln, 4 * kk + qd)];
#pragma unroll
        for (int mi = 0; mi < 4; ++mi) {
          frag8 av = *(const frag8*)&Vs[cb + swi(mi * 16 + ln, 4 * kk + qd)];
          oB[mi] = mfma_bf16(av, bpB, oB[mi]);
          if (actA_pv) oA[mi] = mfma_bf16(av, bpA, oA[mi]);
        }
      }
    }

    // softmax(kt+1) -> Ps rewrite (VALU overlaps PV MFMAs; after Ps reads)
    if (hasNext) {
      softmax_store(sA, j <= qtA, j == qtA, PsA, lA);
      softmax_store(sB, true, j == qtB, PsB, lB);
    }

    __syncthreads();  // drains DMA(kt+2); delimits ring-slot reuse epochs
  }

  lA += __shfl_xor(lA, 16); lA += __shfl_xor(lA, 32);
  lB += __shfl_xor(lB, 16); lB += __shfl_xor(lB, 32);
  float rlA = 1.0f / lA, rlB = 1.0f / lB;

#pragma unroll
  for (int di = 0; di < 4; ++di) {
    ushort4 ov;
    ov.x = f2bf(oA[di][0] * rlA); ov.y = f2bf(oA[di][1] * rlA);
    ov.z = f2bf(oA[di][2] * rlA); ov.w = f2bf(oA[di][3] * rlA);
    *(ushort4*)&O[(size_t)(b * TT + q0A + w * 16 + ln) * DM + h * 64 + di * 16 + qd * 4] = ov;
    ov.x = f2bf(oB[di][0] * rlB); ov.y = f2bf(oB[di][1] * rlB);
    ov.z = f2bf(oB[di][2] * rlB); ov.w = f2bf(oB[di][3] * rlB);
    *(ushort4*)&O[(size_t)(b * TT + q0B + w * 16 + ln) * DM + h * 64 + di * 16 + qd * 4] = ov;
  }
}

extern "C" void kernel_launch(void* const* d_in, const int* in_sizes, int n_in,
                              void* d_out, int out_size, void* d_ws, size_t ws_size,
                              hipStream_t stream) {
  const float* x  = (const float*)d_in[0];
  const float* Wq = (const float*)d_in[1];
  const float* bq = (const float*)d_in[2];
  const float* Wk = (const float*)d_in[3];
  const float* bk = (const float*)d_in[4];
  const float* Wv = (const float*)d_in[5];
  const float* bv = (const float*)d_in[6];
  const float* Wo = (const float*)d_in[7];
  const float* bo = (const float*)d_in[8];

  char* ws = (char*)d_ws;
  const size_t MB = 1ull << 20;
  u16* xbf  = (u16*)(ws + 0);         // 8 MB  (4096 x 1024)
  u16* Wcat = (u16*)(ws + 8 * MB);    // 6 MB  (3072 x 1024: Wq^T|Wk^T|Wv^T)
  u16* Wot  = (u16*)(ws + 14 * MB);   // 2 MB
  u16* QKb  = (u16*)(ws + 16 * MB);   // 16 MB (4096 x 2048)
  u16* Vbb  = (u16*)(ws + 32 * MB);   // 8 MB  (4096 x 1024)
  u16* Vtb  = (u16*)(ws + 40 * MB);   // 8 MB  (32 x 64 x 2048)
  u16* Ob   = (u16*)(ws + 48 * MB);   // 8 MB

  cvt_x_kernel<<<4096, 256, 0, stream>>>(x, xbf);
  transpose_w_kernel<<<dim3(16, 16, 4), 256, 0, stream>>>(
      Wq, Wk, Wv, Wo, Wcat, Wcat + 1024 * 1024, Wcat + 2 * 1024 * 1024, Wot);
  gemm_qkv_kernel<<<dim3(24, 32), 256, 0, stream>>>(
      xbf, Wcat, bq, bk, bv, QKb, Vbb);
  transpose_v_kernel<<<dim3(32, 32), 256, 0, stream>>>(Vbb, Vtb);
  flash7_kernel<<<dim3(16, 32), 256, 0, stream>>>(QKb, Vtb, Ob);
  gemm_out_kernel<<<dim3(16, 32), 256, 0, stream>>>(Ob, Wot, bo, (float*)d_out);
}